// Round 2
// baseline (545.202 us; speedup 1.0000x reference)
//
#include <hip/hip_runtime.h>
#include <math.h>

#define BB 512
#define NN 128
#define FF 128
#define KK 4

typedef __attribute__((ext_vector_type(8))) short bf16x8;
typedef __attribute__((ext_vector_type(4))) float f32x4;

__device__ inline unsigned short f2bf(float x) {
  union { float f; unsigned int u; } v; v.f = x;
  unsigned int r = v.u + 0x7fff + ((v.u >> 16) & 1);   // RNE
  return (unsigned short)(r >> 16);
}
__device__ inline float bf2f(unsigned short h) {
  union { unsigned int u; float f; } v; v.u = ((unsigned int)h) << 16; return v.f;
}

// ---------------------------------------------------------------------------
// PREP: grid-partitioned merge of convE (+degree norm), convH, buildW x3,
// and zeroing of Sum/Cnt. (unchanged from round 1 — never a top dispatch)
// ---------------------------------------------------------------------------
__global__ __launch_bounds__(256) void k_prep(
    const float* __restrict__ E, const float* __restrict__ H,
    const float* __restrict__ RW1, const float* __restrict__ SW1,
    const float* __restrict__ RW2, const float* __restrict__ SW2,
    const float* __restrict__ RW3, const float* __restrict__ SW3,
    unsigned short* __restrict__ Eb, unsigned short* __restrict__ Ha,
    unsigned short* __restrict__ W2L, float* __restrict__ Dv,
    float* __restrict__ Sum, int* __restrict__ Cnt)
{
  const int bid = blockIdx.x;
  if (bid < 16384) {
    int wave = threadIdx.x >> 6;
    int lane = threadIdx.x & 63;
    int row  = bid * 4 + wave;                 // [0, BB*NN)
    const float* p = E + (size_t)row * 512 + lane * 8;
    f32x4 a = *(const f32x4*)p;
    f32x4 b = *(const f32x4*)(p + 4);
    float s = a[0] + a[1] + a[2] + a[3] + b[0] + b[1] + b[2] + b[3];
    #pragma unroll
    for (int off = 32; off > 0; off >>= 1) s += __shfl_down(s, off, 64);
    if (lane == 0) Dv[row] = 1.0f / (s + 4.0f);
    union { unsigned short h[8]; f32x4 v; } u;
    u.h[0] = f2bf(a[0]); u.h[1] = f2bf(a[1]); u.h[2] = f2bf(a[2]); u.h[3] = f2bf(a[3]);
    u.h[4] = f2bf(b[0]); u.h[5] = f2bf(b[1]); u.h[6] = f2bf(b[2]); u.h[7] = f2bf(b[3]);
    *(f32x4*)(Eb + (size_t)row * 512 + lane * 8) = u.v;
  } else if (bid < 20480) {
    size_t i = ((size_t)(bid - 16384) * 256 + threadIdx.x) * 8;
    f32x4 a = *(const f32x4*)(H + i);
    f32x4 b = *(const f32x4*)(H + i + 4);
    union { unsigned short h[8]; f32x4 v; } u;
    u.h[0] = f2bf(a[0]); u.h[1] = f2bf(a[1]); u.h[2] = f2bf(a[2]); u.h[3] = f2bf(a[3]);
    u.h[4] = f2bf(b[0]); u.h[5] = f2bf(b[1]); u.h[6] = f2bf(b[2]); u.h[7] = f2bf(b[3]);
    *(f32x4*)(Ha + i) = u.v;
  } else {
    int t2  = bid - 20480;                     // [0, 960)
    int tab = t2 / 320;
    int idx = (t2 - tab * 320) * 256 + threadIdx.x;  // [0, 81920)
    int m = idx & 127;
    int c = idx >> 7;
    const float* RW = (tab == 0) ? RW1 : (tab == 1) ? RW2 : RW3;
    const float* SW = (tab == 0) ? SW1 : (tab == 1) ? SW2 : SW3;
    float v = (c < 512) ? RW[m * 512 + c] : SW[m * 128 + (c - 512)];
    W2L[(size_t)tab * 81920 + idx] = f2bf(v);
    if (t2 == 0 && threadIdx.x == 0) { *Sum = 0.0f; *Cnt = 0; }
  }
}

// ---------------------------------------------------------------------------
// A: Gt[b][n][j*4+k] = sum_m W2[n*4+k][m] * H[b][j][m]   (RW rows 0..511)
// One 512-thread block per graph; 8 waves x 64 c-rows; NO LDS, NO barriers.
// Identical fragment/index math to the proven phase-1a; output to global.
// ---------------------------------------------------------------------------
__device__ __forceinline__ void gA_body(
    const unsigned short* __restrict__ H_b,   // [128][128] bf16
    const unsigned short* __restrict__ W2,    // [640][128] bf16 (rows 0..511 used)
    unsigned short* __restrict__ G_b,         // [128][512] bf16 out
    int tid)
{
  const int w = tid >> 6, l = tid & 63;
  const int lq = l >> 4, lm = l & 15;

  bf16x8 fa[4][4];
  #pragma unroll
  for (int f = 0; f < 4; ++f)
    #pragma unroll
    for (int k0 = 0; k0 < 4; ++k0)
      fa[f][k0] = *(const bf16x8*)(W2 + (w * 64 + f * 16 + lm) * 128 + k0 * 32 + lq * 8);

  #pragma unroll 2
  for (int g = 0; g < 8; ++g) {
    bf16x8 fbk[4];
    #pragma unroll
    for (int k0 = 0; k0 < 4; ++k0)
      fbk[k0] = *(const bf16x8*)(H_b + (g * 16 + lm) * 128 + k0 * 32 + lq * 8);
    f32x4 gacc[4] = {};
    #pragma unroll
    for (int k0 = 0; k0 < 4; ++k0)
      #pragma unroll
      for (int f = 0; f < 4; ++f)
        gacc[f] = __builtin_amdgcn_mfma_f32_16x16x32_bf16(fa[f][k0], fbk[k0], gacc[f], 0, 0, 0);
    #pragma unroll
    for (int f = 0; f < 4; ++f) {
      int n = w * 16 + f * 4 + lq;             // c = n*4 + reg(k)
      union { unsigned short h4[4]; uint2 v; } u;
      u.h4[0] = f2bf(gacc[f][0]); u.h4[1] = f2bf(gacc[f][1]);
      u.h4[2] = f2bf(gacc[f][2]); u.h4[3] = f2bf(gacc[f][3]);
      *(uint2*)(G_b + (size_t)n * 512 + (g * 16 + lm) * 4) = u.v;
    }
  }
}

__global__ __launch_bounds__(512, 2) void k_gA(
    const unsigned short* __restrict__ Hin,
    const unsigned short* __restrict__ W2,
    unsigned short* __restrict__ Gt)
{
  const int b = blockIdx.x;
  gA_body(Hin + (size_t)b * 16384, W2, Gt + (size_t)b * 65536, threadIdx.x);
}

// ---------------------------------------------------------------------------
// B: msg = E[b] @ Gt[b]^T (K=512) + S = H[b] @ SW, sigmoid-fused -> Hout.
// All operands global-direct (L1/L2-hot); only 2 barriers (output staging).
// FUSEA: then compute Gt_next = W2nxt_RW @ Hout^T (block-local dep via L2).
// DOMLP: then MLP head + atomic-counted final mean.
// ---------------------------------------------------------------------------
template<int FUSEA, int DOMLP>
__global__ __launch_bounds__(512, 2) void k_gB(
    const unsigned short* __restrict__ Eb,    // [B][128][512]
    const unsigned short* __restrict__ Gin,   // [B][128][512]
    const unsigned short* __restrict__ Hin,   // [B][128][128]
    const unsigned short* __restrict__ W2cur, // [640][128] (rows 512.. used)
    const unsigned short* __restrict__ W2nxt, // [640][128] (rows 0..511 used)
    const float* __restrict__ Dv,             // [B][128]
    unsigned short* __restrict__ Hout,        // [B][128][128]
    unsigned short* __restrict__ Gout,        // [B][128][512]
    const float* __restrict__ W1, const float* __restrict__ b1,
    const float* __restrict__ W2w, const float* __restrict__ b2,
    float* __restrict__ Sum, int* __restrict__ Cnt, float* __restrict__ out)
{
  __shared__ unsigned short Os[128 * 128];

  const int b = blockIdx.x, tid = threadIdx.x;
  const int w = tid >> 6, l = tid & 63;
  const int wr = w >> 1, wc = w & 1;
  const int lq = l >> 4, lm = l & 15;

  const unsigned short* E_b = Eb  + (size_t)b * 65536;
  const unsigned short* G_b = Gin + (size_t)b * 65536;
  const unsigned short* H_b = Hin + (size_t)b * 16384;
  unsigned short*       O_b = Hout + (size_t)b * 16384;

  // ---- phase 2: macc = E @ Gt^T over K = 512 (j,k pairs) ----
  f32x4 macc[2][4] = {};
  #pragma unroll 4
  for (int kt = 0; kt < 16; ++kt) {
    bf16x8 ea[2], fb[4];
    #pragma unroll
    for (int f = 0; f < 2; ++f)
      ea[f] = *(const bf16x8*)(E_b + (size_t)(wr * 32 + f * 16 + lm) * 512 + kt * 32 + lq * 8);
    #pragma unroll
    for (int g = 0; g < 4; ++g)
      fb[g] = *(const bf16x8*)(G_b + (size_t)(wc * 64 + g * 16 + lm) * 512 + kt * 32 + lq * 8);
    #pragma unroll
    for (int f = 0; f < 2; ++f)
      #pragma unroll
      for (int g = 0; g < 4; ++g)
        macc[f][g] = __builtin_amdgcn_mfma_f32_16x16x32_bf16(ea[f], fb[g], macc[f][g], 0, 0, 0);
  }

  // ---- phase 1b: sacc = Hin @ SW (rows 512..639 of W2cur) ----
  f32x4 sacc[2][4] = {};
  #pragma unroll
  for (int k0 = 0; k0 < 128; k0 += 32) {
    bf16x8 fa[2], fb[4];
    #pragma unroll
    for (int f = 0; f < 2; ++f)
      fa[f] = *(const bf16x8*)(H_b + (wr * 32 + f * 16 + lm) * 128 + k0 + lq * 8);
    #pragma unroll
    for (int g = 0; g < 4; ++g)
      fb[g] = *(const bf16x8*)(W2cur + (512 + wc * 64 + g * 16 + lm) * 128 + k0 + lq * 8);
    #pragma unroll
    for (int f = 0; f < 2; ++f)
      #pragma unroll
      for (int g = 0; g < 4; ++g)
        sacc[f][g] = __builtin_amdgcn_mfma_f32_16x16x32_bf16(fa[f], fb[g], sacc[f][g], 0, 0, 0);
  }

  // ---- epilogue: fuse, stage rows in Os, coalesced 64B/thread stores ----
  const float* dvb = Dv + b * 128;
  #pragma unroll
  for (int f = 0; f < 2; ++f) {
    int i0 = wr * 32 + f * 16 + lq * 4;
    f32x4 d = *(const f32x4*)(dvb + i0);
    #pragma unroll
    for (int g = 0; g < 4; ++g) {
      int n = wc * 64 + g * 16 + lm;
      #pragma unroll
      for (int r = 0; r < 4; ++r) {
        float v = fmaf(macc[f][g][r], d[r], sacc[f][g][r]);
        Os[(i0 + r) * 128 + n] = f2bf(1.0f / (1.0f + __expf(-v)));
      }
    }
  }
  __syncthreads();
  {
    int off = tid * 32;                        // 32 ushorts = 64 B per thread
    f32x4 v0 = *(const f32x4*)(Os + off);
    f32x4 v1 = *(const f32x4*)(Os + off + 8);
    f32x4 v2 = *(const f32x4*)(Os + off + 16);
    f32x4 v3 = *(const f32x4*)(Os + off + 24);
    *(f32x4*)(O_b + off)      = v0;
    *(f32x4*)(O_b + off + 8)  = v1;
    *(f32x4*)(O_b + off + 16) = v2;
    *(f32x4*)(O_b + off + 24) = v3;
  }

  if (FUSEA) {
    __syncthreads();   // drain O_b stores to L2; block-local read-after-write
    gA_body(O_b, W2nxt, Gout + (size_t)b * 65536, tid);
  }

  if (DOMLP) {
    __syncthreads();   // drain O_b stores; Os free for reuse as f32 scratch
    float* W1s = (float*)Os;            // 2560 floats
    float* b1s = W1s + 2560;            // 20
    float* W2s = b1s + 32;              // 20
    float* red = W2s + 32;              // 512
    for (int i = tid; i < 2560; i += 512) W1s[i] = W1[i];
    if (tid < 20) { b1s[tid] = b1[tid]; W2s[tid] = W2w[tid]; }
    __syncthreads();

    float s = 0.0f;
    if (tid < 128) {
      const unsigned short* hr = O_b + (size_t)tid * 128;
      float h[20];
      #pragma unroll
      for (int j = 0; j < 20; ++j) h[j] = b1s[j];
      for (int m8 = 0; m8 < 128; m8 += 8) {
        f32x4 pk = *(const f32x4*)(hr + m8);
        const unsigned short* us = (const unsigned short*)&pk;
        #pragma unroll
        for (int e = 0; e < 8; ++e) {
          float x = bf2f(us[e]);
          #pragma unroll
          for (int j = 0; j < 20; ++j) h[j] = fmaf(x, W1s[(m8 + e) * 20 + j], h[j]);
        }
      }
      float v = b2[0];
      #pragma unroll
      for (int j = 0; j < 20; ++j) {
        float t = h[j];
        t = fmaxf(t, 0.1f * t);
        v = fmaf(t, W2s[j], v);
      }
      s = 1.0f / (1.0f + __expf(-v));
    }

    red[tid] = s;
    __syncthreads();
    #pragma unroll
    for (int off = 256; off > 0; off >>= 1) {
      if (tid < off) red[tid] += red[tid + off];
      __syncthreads();
    }
    if (tid == 0) {
      atomicAdd(Sum, red[0]);
      __threadfence();
      int v = atomicAdd(Cnt, 1);
      if (v == BB - 1) {
        float tot = atomicAdd(Sum, 0.0f);
        out[0] = tot * (1.0f / 65536.0f);
      }
    }
  }
}

// ---------------------------------------------------------------------------
extern "C" void kernel_launch(void* const* d_in, const int* in_sizes, int n_in,
                              void* d_out, int out_size, void* d_ws, size_t ws_size,
                              hipStream_t stream) {
  (void)in_sizes; (void)n_in; (void)out_size; (void)ws_size;
  const float* H   = (const float*)d_in[0];
  const float* E   = (const float*)d_in[1];
  const float* RW1 = (const float*)d_in[2];
  const float* SW1 = (const float*)d_in[3];
  const float* RW2 = (const float*)d_in[4];
  const float* SW2 = (const float*)d_in[5];
  const float* RW3 = (const float*)d_in[6];
  const float* SW3 = (const float*)d_in[7];
  const float* W1  = (const float*)d_in[8];
  const float* b1  = (const float*)d_in[9];
  const float* W2  = (const float*)d_in[10];
  const float* b2  = (const float*)d_in[11];
  float* out = (float*)d_out;

  char* w = (char*)d_ws;
  float*          wsD   = (float*)w;           w += (size_t)65536 * 4;
  unsigned short* wsEb  = (unsigned short*)w;  w += (size_t)33554432 * 2;   // 64 MB
  unsigned short* wsG1  = (unsigned short*)w;  w += (size_t)33554432 * 2;   // 64 MB
  unsigned short* wsG2  = (unsigned short*)w;  w += (size_t)33554432 * 2;   // 64 MB
  unsigned short* wsHa  = (unsigned short*)w;  w += (size_t)8388608 * 2;
  unsigned short* wsHb  = (unsigned short*)w;  w += (size_t)8388608 * 2;
  unsigned short* wsHc  = (unsigned short*)w;  w += (size_t)8388608 * 2;
  unsigned short* wsHd  = (unsigned short*)w;  w += (size_t)8388608 * 2;
  unsigned short* wsW2  = (unsigned short*)w;  w += (size_t)3 * 81920 * 2;
  float*          wsSum = (float*)w;           w += 64;
  int*            wsCnt = (int*)w;             w += 64;

  // 5 dispatches total
  k_prep<<<21440, 256, 0, stream>>>(E, H, RW1, SW1, RW2, SW2, RW3, SW3,
                                    wsEb, wsHa, wsW2, wsD, wsSum, wsCnt);

  // layer 1 producer
  k_gA<<<BB, 512, 0, stream>>>(wsHa, wsW2, wsG1);

  // B(1) + A(2)
  k_gB<1, 0><<<BB, 512, 0, stream>>>(wsEb, wsG1, wsHa, wsW2, wsW2 + 81920,
                                     wsD, wsHb, wsG2,
                                     W1, b1, W2, b2, wsSum, wsCnt, out);
  // B(2) + A(3)
  k_gB<1, 0><<<BB, 512, 0, stream>>>(wsEb, wsG2, wsHb, wsW2 + 81920, wsW2 + 163840,
                                     wsD, wsHc, wsG1,
                                     W1, b1, W2, b2, wsSum, wsCnt, out);
  // B(3) + MLP + final
  k_gB<0, 1><<<BB, 512, 0, stream>>>(wsEb, wsG1, wsHc, wsW2 + 163840, wsW2,
                                     wsD, wsHd, wsG2,
                                     W1, b1, W2, b2, wsSum, wsCnt, out);
}

// Round 3
// 503.562 us; speedup vs baseline: 1.0827x; 1.0827x over previous
//
#include <hip/hip_runtime.h>
#include <math.h>

#define BB 512
#define NN 128
#define FF 128
#define KK 4
#define GT_PITCH 520   // ushorts; 1040B rows -> 16B bank offset per row (2-way max)
#define OS_PITCH 40    // ushorts

typedef __attribute__((ext_vector_type(8))) short bf16x8;
typedef __attribute__((ext_vector_type(4))) float f32x4;

__device__ inline unsigned short f2bf(float x) {
  union { float f; unsigned int u; } v; v.f = x;
  unsigned int r = v.u + 0x7fff + ((v.u >> 16) & 1);   // RNE
  return (unsigned short)(r >> 16);
}
__device__ inline float bf2f(unsigned short h) {
  union { unsigned int u; float f; } v; v.u = ((unsigned int)h) << 16; return v.f;
}

// ---------------------------------------------------------------------------
// PREP: convE (+degree norm) | convH | buildW x3 | zero Sum/Cnt  (proven)
// ---------------------------------------------------------------------------
__global__ __launch_bounds__(256) void k_prep(
    const float* __restrict__ E, const float* __restrict__ H,
    const float* __restrict__ RW1, const float* __restrict__ SW1,
    const float* __restrict__ RW2, const float* __restrict__ SW2,
    const float* __restrict__ RW3, const float* __restrict__ SW3,
    unsigned short* __restrict__ Eb, unsigned short* __restrict__ Ha,
    unsigned short* __restrict__ W2L, float* __restrict__ Dv,
    float* __restrict__ Sum, int* __restrict__ Cnt)
{
  const int bid = blockIdx.x;
  if (bid < 16384) {
    int wave = threadIdx.x >> 6;
    int lane = threadIdx.x & 63;
    int row  = bid * 4 + wave;                 // [0, BB*NN)
    const float* p = E + (size_t)row * 512 + lane * 8;
    f32x4 a = *(const f32x4*)p;
    f32x4 b = *(const f32x4*)(p + 4);
    float s = a[0] + a[1] + a[2] + a[3] + b[0] + b[1] + b[2] + b[3];
    #pragma unroll
    for (int off = 32; off > 0; off >>= 1) s += __shfl_down(s, off, 64);
    if (lane == 0) Dv[row] = 1.0f / (s + 4.0f);
    union { unsigned short h[8]; f32x4 v; } u;
    u.h[0] = f2bf(a[0]); u.h[1] = f2bf(a[1]); u.h[2] = f2bf(a[2]); u.h[3] = f2bf(a[3]);
    u.h[4] = f2bf(b[0]); u.h[5] = f2bf(b[1]); u.h[6] = f2bf(b[2]); u.h[7] = f2bf(b[3]);
    *(f32x4*)(Eb + (size_t)row * 512 + lane * 8) = u.v;
  } else if (bid < 20480) {
    size_t i = ((size_t)(bid - 16384) * 256 + threadIdx.x) * 8;
    f32x4 a = *(const f32x4*)(H + i);
    f32x4 b = *(const f32x4*)(H + i + 4);
    union { unsigned short h[8]; f32x4 v; } u;
    u.h[0] = f2bf(a[0]); u.h[1] = f2bf(a[1]); u.h[2] = f2bf(a[2]); u.h[3] = f2bf(a[3]);
    u.h[4] = f2bf(b[0]); u.h[5] = f2bf(b[1]); u.h[6] = f2bf(b[2]); u.h[7] = f2bf(b[3]);
    *(f32x4*)(Ha + i) = u.v;
  } else {
    int t2  = bid - 20480;                     // [0, 960)
    int tab = t2 / 320;
    int idx = (t2 - tab * 320) * 256 + threadIdx.x;  // [0, 81920)
    int m = idx & 127;
    int c = idx >> 7;
    const float* RW = (tab == 0) ? RW1 : (tab == 1) ? RW2 : RW3;
    const float* SW = (tab == 0) ? SW1 : (tab == 1) ? SW2 : SW3;
    float v = (c < 512) ? RW[m * 512 + c] : SW[m * 128 + (c - 512)];
    W2L[(size_t)tab * 81920 + idx] = f2bf(v);
    if (t2 == 0 && threadIdx.x == 0) { *Sum = 0.0f; *Cnt = 0; }
  }
}

// ---------------------------------------------------------------------------
// LAYER: block = (graph b, n-quarter q). 256 threads = 4 waves.
//  A: GtL[n_l][j*4+k] = sum_m W2[128q + 4*n_l + k][m] * H[b][j][m]  (LDS 32.5KB)
//  B: macc = E[b] @ GtL^T  (K=512, E direct from global/L3)
//  1b: sacc = H[b] @ SW[q-cols]
//  epi: sigmoid(macc*D + sacc) -> stage Os -> coalesced 32B/thread stores
// Quarters partition c exactly: zero redundant FLOPs, zero Gt global traffic.
// ---------------------------------------------------------------------------
__global__ __launch_bounds__(256, 4) void k_L(
    const unsigned short* __restrict__ Eb,    // [B][128][512]
    const unsigned short* __restrict__ Hin,   // [B][128][128]
    const unsigned short* __restrict__ W2c,   // [640][128]
    const float* __restrict__ Dv,             // [B][128]
    unsigned short* __restrict__ Hout)        // [B][128][128]
{
  __shared__ unsigned short GtL[32 * GT_PITCH];   // overlaid by Os after barrier

  // XCD-contiguous swizzle (2048 % 8 == 0, bijective): keeps a graph's 4
  // quarter-blocks on one XCD for E/H L2 reuse.
  const int nwg = gridDim.x;
  const int cpx = nwg >> 3;
  const int wg  = (blockIdx.x & 7) * cpx + (blockIdx.x >> 3);
  const int b = wg >> 2, q = wg & 3;

  const int tid = threadIdx.x;
  const int w = tid >> 6, l = tid & 63;
  const int lq = l >> 4, lm = l & 15;

  const unsigned short* E_b = Eb  + (size_t)b * 65536;
  const unsigned short* H_b = Hin + (size_t)b * 16384;

  // ---- A: Gt quarter into LDS (index math = r0 phase-1a + Gs-write) ----
  bf16x8 fa[2][4];
  #pragma unroll
  for (int f = 0; f < 2; ++f)
    #pragma unroll
    for (int k0 = 0; k0 < 4; ++k0)
      fa[f][k0] = *(const bf16x8*)(W2c + (q * 128 + w * 32 + f * 16 + lm) * 128 + k0 * 32 + lq * 8);

  #pragma unroll 1
  for (int jh = 0; jh < 2; ++jh) {
    f32x4 gacc[2][4] = {};
    #pragma unroll
    for (int k0 = 0; k0 < 4; ++k0) {
      bf16x8 fb[4];
      #pragma unroll
      for (int g = 0; g < 4; ++g)
        fb[g] = *(const bf16x8*)(H_b + (jh * 64 + g * 16 + lm) * 128 + k0 * 32 + lq * 8);
      #pragma unroll
      for (int f = 0; f < 2; ++f)
        #pragma unroll
        for (int g = 0; g < 4; ++g)
          gacc[f][g] = __builtin_amdgcn_mfma_f32_16x16x32_bf16(fa[f][k0], fb[g], gacc[f][g], 0, 0, 0);
    }
    #pragma unroll
    for (int f = 0; f < 2; ++f) {
      int n_l = w * 8 + f * 4 + lq;            // c_local = 4*n_l + reg(k)
      #pragma unroll
      for (int g = 0; g < 4; ++g) {
        int jl = jh * 64 + g * 16 + lm;
        union { unsigned short h4[4]; uint2 v; } u;
        u.h4[0] = f2bf(gacc[f][g][0]); u.h4[1] = f2bf(gacc[f][g][1]);
        u.h4[2] = f2bf(gacc[f][g][2]); u.h4[3] = f2bf(gacc[f][g][3]);
        *(uint2*)(&GtL[n_l * GT_PITCH + jl * 4]) = u.v;
      }
    }
  }
  __syncthreads();

  // ---- B: macc = E @ GtL^T over K=512 (index math = r2 phase-2) ----
  f32x4 macc[2][2] = {};
  #pragma unroll 4
  for (int kt = 0; kt < 16; ++kt) {
    bf16x8 ea[2], fb[2];
    #pragma unroll
    for (int f = 0; f < 2; ++f)
      ea[f] = *(const bf16x8*)(E_b + (size_t)(w * 32 + f * 16 + lm) * 512 + kt * 32 + lq * 8);
    #pragma unroll
    for (int g = 0; g < 2; ++g)
      fb[g] = *(const bf16x8*)(&GtL[(g * 16 + lm) * GT_PITCH + kt * 32 + lq * 8]);
    #pragma unroll
    for (int f = 0; f < 2; ++f)
      #pragma unroll
      for (int g = 0; g < 2; ++g)
        macc[f][g] = __builtin_amdgcn_mfma_f32_16x16x32_bf16(ea[f], fb[g], macc[f][g], 0, 0, 0);
  }

  // ---- 1b: sacc = H @ SW (rows 512+32q.. of W2c; r2 phase-1b) ----
  f32x4 sacc[2][2] = {};
  #pragma unroll
  for (int k0 = 0; k0 < 128; k0 += 32) {
    bf16x8 ha[2], sb[2];
    #pragma unroll
    for (int f = 0; f < 2; ++f)
      ha[f] = *(const bf16x8*)(H_b + (w * 32 + f * 16 + lm) * 128 + k0 + lq * 8);
    #pragma unroll
    for (int g = 0; g < 2; ++g)
      sb[g] = *(const bf16x8*)(W2c + (512 + q * 32 + g * 16 + lm) * 128 + k0 + lq * 8);
    #pragma unroll
    for (int f = 0; f < 2; ++f)
      #pragma unroll
      for (int g = 0; g < 2; ++g)
        sacc[f][g] = __builtin_amdgcn_mfma_f32_16x16x32_bf16(ha[f], sb[g], sacc[f][g], 0, 0, 0);
  }

  __syncthreads();   // all GtL readers done; overlay Os
  unsigned short* Os = GtL;   // [128][OS_PITCH]

  const float* dvb = Dv + b * 128;
  #pragma unroll
  for (int f = 0; f < 2; ++f) {
    int i0 = w * 32 + f * 16 + lq * 4;
    f32x4 d = *(const f32x4*)(dvb + i0);
    #pragma unroll
    for (int g = 0; g < 2; ++g) {
      int nn = g * 16 + lm;
      #pragma unroll
      for (int r = 0; r < 4; ++r) {
        float v = fmaf(macc[f][g][r], d[r], sacc[f][g][r]);
        Os[(i0 + r) * OS_PITCH + nn] = f2bf(1.0f / (1.0f + __expf(-v)));
      }
    }
  }
  __syncthreads();
  {
    int i = tid >> 1, half = tid & 1;          // 32B per thread
    f32x4 v0 = *(const f32x4*)(Os + i * OS_PITCH + half * 16);
    f32x4 v1 = *(const f32x4*)(Os + i * OS_PITCH + half * 16 + 8);
    unsigned short* dst = Hout + (size_t)b * 16384 + i * 128 + q * 32 + half * 16;
    *(f32x4*)dst       = v0;
    *(f32x4*)(dst + 8) = v1;
  }
}

// ---------------------------------------------------------------------------
// MLP head + atomic-counted final mean (proven r0 body + r1/r2 tail)
// ---------------------------------------------------------------------------
__global__ __launch_bounds__(256) void k_mlp(
    const unsigned short* __restrict__ H,   // [B*N][128] bf16
    const float* __restrict__ W1, const float* __restrict__ b1,
    const float* __restrict__ W2, const float* __restrict__ b2,
    float* __restrict__ Sum, int* __restrict__ Cnt, float* __restrict__ out)
{
  __shared__ float W1s[128 * 20];
  __shared__ float b1s[20], W2s[20];
  __shared__ float red[256];
  for (int i = threadIdx.x; i < 2560; i += 256) W1s[i] = W1[i];
  if (threadIdx.x < 20) { b1s[threadIdx.x] = b1[threadIdx.x]; W2s[threadIdx.x] = W2[threadIdx.x]; }
  __syncthreads();

  int row = blockIdx.x * 256 + threadIdx.x;
  float h[20];
  #pragma unroll
  for (int j = 0; j < 20; ++j) h[j] = b1s[j];
  const unsigned short* hr = H + (size_t)row * 128;
  for (int m8 = 0; m8 < 128; m8 += 8) {
    f32x4 pk = *(const f32x4*)(hr + m8);
    const unsigned short* us = (const unsigned short*)&pk;
    #pragma unroll
    for (int e = 0; e < 8; ++e) {
      float x = bf2f(us[e]);
      #pragma unroll
      for (int j = 0; j < 20; ++j) h[j] = fmaf(x, W1s[(m8 + e) * 20 + j], h[j]);
    }
  }
  float v = b2[0];
  #pragma unroll
  for (int j = 0; j < 20; ++j) {
    float t = h[j];
    t = fmaxf(t, 0.1f * t);
    v = fmaf(t, W2s[j], v);
  }
  float s = 1.0f / (1.0f + __expf(-v));

  red[threadIdx.x] = s;
  __syncthreads();
  #pragma unroll
  for (int off = 128; off > 0; off >>= 1) {
    if (threadIdx.x < off) red[threadIdx.x] += red[threadIdx.x + off];
    __syncthreads();
  }
  if (threadIdx.x == 0) {
    atomicAdd(Sum, red[0]);
    __threadfence();
    int c = atomicAdd(Cnt, 1);
    if (c == gridDim.x - 1) {
      float tot = atomicAdd(Sum, 0.0f);
      out[0] = tot * (1.0f / 65536.0f);
    }
  }
}

// ---------------------------------------------------------------------------
extern "C" void kernel_launch(void* const* d_in, const int* in_sizes, int n_in,
                              void* d_out, int out_size, void* d_ws, size_t ws_size,
                              hipStream_t stream) {
  (void)in_sizes; (void)n_in; (void)out_size; (void)ws_size;
  const float* H   = (const float*)d_in[0];
  const float* E   = (const float*)d_in[1];
  const float* RW1 = (const float*)d_in[2];
  const float* SW1 = (const float*)d_in[3];
  const float* RW2 = (const float*)d_in[4];
  const float* SW2 = (const float*)d_in[5];
  const float* RW3 = (const float*)d_in[6];
  const float* SW3 = (const float*)d_in[7];
  const float* W1  = (const float*)d_in[8];
  const float* b1  = (const float*)d_in[9];
  const float* W2  = (const float*)d_in[10];
  const float* b2  = (const float*)d_in[11];
  float* out = (float*)d_out;

  char* w = (char*)d_ws;
  float*          wsD   = (float*)w;           w += (size_t)65536 * 4;
  unsigned short* wsEb  = (unsigned short*)w;  w += (size_t)33554432 * 2;   // 64 MB
  unsigned short* wsHa  = (unsigned short*)w;  w += (size_t)8388608 * 2;
  unsigned short* wsHb  = (unsigned short*)w;  w += (size_t)8388608 * 2;
  unsigned short* wsHc  = (unsigned short*)w;  w += (size_t)8388608 * 2;
  unsigned short* wsHd  = (unsigned short*)w;  w += (size_t)8388608 * 2;
  unsigned short* wsW2  = (unsigned short*)w;  w += (size_t)3 * 81920 * 2;
  float*          wsSum = (float*)w;           w += 64;
  int*            wsCnt = (int*)w;             w += 64;

  // 5 dispatches; working set (Eb + 2 live H + W2) ~ 100 MB -> L3-resident
  k_prep<<<21440, 256, 0, stream>>>(E, H, RW1, SW1, RW2, SW2, RW3, SW3,
                                    wsEb, wsHa, wsW2, wsD, wsSum, wsCnt);

  k_L<<<BB * 4, 256, 0, stream>>>(wsEb, wsHa, wsW2,          wsD, wsHb);
  k_L<<<BB * 4, 256, 0, stream>>>(wsEb, wsHb, wsW2 + 81920,  wsD, wsHc);
  k_L<<<BB * 4, 256, 0, stream>>>(wsEb, wsHc, wsW2 + 163840, wsD, wsHd);

  k_mlp<<<BB * NN / 256, 256, 0, stream>>>(wsHd, W1, b1, W2, b2, wsSum, wsCnt, out);
}

// Round 5
// 427.973 us; speedup vs baseline: 1.2739x; 1.1766x over previous
//
#include <hip/hip_runtime.h>
#include <math.h>

#define BB 512
#define NN 128
#define FF 128
#define KK 4
#define GS_PITCH 132

typedef __attribute__((ext_vector_type(8))) short bf16x8;
typedef __attribute__((ext_vector_type(4))) float f32x4;

__device__ inline unsigned short f2bf(float x) {
  union { float f; unsigned int u; } v; v.f = x;
  unsigned int r = v.u + 0x7fff + ((v.u >> 16) & 1);   // RNE
  return (unsigned short)(r >> 16);
}
__device__ inline float bf2f(unsigned short h) {
  union { unsigned int u; float f; } v; v.u = ((unsigned int)h) << 16; return v.f;
}

// async global->LDS, 16B per lane; lds dest = wave-uniform base + lane*16
__device__ inline void g2l16(const unsigned short* gptr, unsigned short* lptr) {
  __builtin_amdgcn_global_load_lds(
      (const __attribute__((address_space(1))) unsigned int*)gptr,
      (__attribute__((address_space(3))) unsigned int*)lptr, 16, 0, 0);
}

// ---------------------------------------------------------------------------
// PREP: convE (+degree norm) | convH | buildW x3 | zero Sum/Cnt  (proven r1-r3)
// ---------------------------------------------------------------------------
__global__ __launch_bounds__(256) void k_prep(
    const float* __restrict__ E, const float* __restrict__ H,
    const float* __restrict__ RW1, const float* __restrict__ SW1,
    const float* __restrict__ RW2, const float* __restrict__ SW2,
    const float* __restrict__ RW3, const float* __restrict__ SW3,
    unsigned short* __restrict__ Eb, unsigned short* __restrict__ Ha,
    unsigned short* __restrict__ W2L, float* __restrict__ Dv,
    float* __restrict__ Sum, int* __restrict__ Cnt)
{
  const int bid = blockIdx.x;
  if (bid < 16384) {
    int wave = threadIdx.x >> 6;
    int lane = threadIdx.x & 63;
    int row  = bid * 4 + wave;                 // [0, BB*NN)
    const float* p = E + (size_t)row * 512 + lane * 8;
    f32x4 a = *(const f32x4*)p;
    f32x4 b = *(const f32x4*)(p + 4);
    float s = a[0] + a[1] + a[2] + a[3] + b[0] + b[1] + b[2] + b[3];
    #pragma unroll
    for (int off = 32; off > 0; off >>= 1) s += __shfl_down(s, off, 64);
    if (lane == 0) Dv[row] = 1.0f / (s + 4.0f);
    union { unsigned short h[8]; f32x4 v; } u;
    u.h[0] = f2bf(a[0]); u.h[1] = f2bf(a[1]); u.h[2] = f2bf(a[2]); u.h[3] = f2bf(a[3]);
    u.h[4] = f2bf(b[0]); u.h[5] = f2bf(b[1]); u.h[6] = f2bf(b[2]); u.h[7] = f2bf(b[3]);
    *(f32x4*)(Eb + (size_t)row * 512 + lane * 8) = u.v;
  } else if (bid < 20480) {
    size_t i = ((size_t)(bid - 16384) * 256 + threadIdx.x) * 8;
    f32x4 a = *(const f32x4*)(H + i);
    f32x4 b = *(const f32x4*)(H + i + 4);
    union { unsigned short h[8]; f32x4 v; } u;
    u.h[0] = f2bf(a[0]); u.h[1] = f2bf(a[1]); u.h[2] = f2bf(a[2]); u.h[3] = f2bf(a[3]);
    u.h[4] = f2bf(b[0]); u.h[5] = f2bf(b[1]); u.h[6] = f2bf(b[2]); u.h[7] = f2bf(b[3]);
    *(f32x4*)(Ha + i) = u.v;
  } else {
    int t2  = bid - 20480;                     // [0, 960)
    int tab = t2 / 320;
    int idx = (t2 - tab * 320) * 256 + threadIdx.x;  // [0, 81920)
    int m = idx & 127;
    int c = idx >> 7;
    const float* RW = (tab == 0) ? RW1 : (tab == 1) ? RW2 : RW3;
    const float* SW = (tab == 0) ? SW1 : (tab == 1) ? SW2 : SW3;
    float v = (c < 512) ? RW[m * 512 + c] : SW[m * 128 + (c - 512)];
    W2L[(size_t)tab * 81920 + idx] = f2bf(v);
    if (t2 == 0 && threadIdx.x == 0) { *Sum = 0.0f; *Cnt = 0; }
  }
}

// ---------------------------------------------------------------------------
// Fused RGCN layer: EXACT copy of the round-0 proven k_layer (measured best,
// ~50 us/layer), one 512-thread block (8 waves) per graph.
// DOMLP tail = round-2's proven MLP+finalize path (reads O_b back L2-hot).
// ---------------------------------------------------------------------------
template<int DOMLP>
__global__ __launch_bounds__(512, 2) void k_layer(
    const unsigned short* __restrict__ Eb,   // [B][128][512]
    const unsigned short* __restrict__ Hin,  // [B][128][128]
    const unsigned short* __restrict__ W2L,  // [640][128]
    const float* __restrict__ Dv,            // [B][128]
    unsigned short* __restrict__ Hout,       // [B][128][128]
    const float* __restrict__ W1, const float* __restrict__ b1,
    const float* __restrict__ W2w, const float* __restrict__ b2,
    float* __restrict__ Sum, int* __restrict__ Cnt, float* __restrict__ out)
{
  __shared__ unsigned short Gs[128 * GS_PITCH];
  __shared__ unsigned short Es[128 * 128];

  const int b = blockIdx.x;
  const unsigned short* E_b = Eb  + (size_t)b * 65536;
  const unsigned short* H_b = Hin + (size_t)b * 16384;

  const int tid = threadIdx.x;
  const int w = tid >> 6, l = tid & 63;
  const int wr = w >> 1, wc = w & 1;
  const int lq = l >> 4, lm = l & 15;

  f32x4 macc[2][4] = {};

  for (int s = 0; s < 4; ++s) {
    if (s) __syncthreads();   // prev strip's Es/Gs readers done

    // ---- hoisted k0=0 fragment loads for phase 1a ----
    bf16x8 fa0[4], fb0[2];
    #pragma unroll
    for (int f = 0; f < 4; ++f)
      fa0[f] = *(const bf16x8*)(W2L + (w * 64 + f * 16 + lm) * 128 + lq * 8);
    #pragma unroll
    for (int g = 0; g < 2; ++g)
      fb0[g] = *(const bf16x8*)(H_b + (s * 32 + g * 16 + lm) * 128 + lq * 8);

    // ---- issue async Es DMA (swizzled): slot cb holds global cb^(row&15) ----
    #pragma unroll
    for (int r = 0; r < 4; ++r) {
      int R   = r * 32 + w * 4 + (l >> 4);
      int cbg = (l & 15) ^ (R & 15);
      g2l16(E_b + R * 512 + s * 128 + cbg * 8,
            Es + (r * 32 + w * 4) * 128);      // wave-uniform base; +lane*16B in HW
    }

    // ---- phase 1a: Gs = W2 @ H^T for j in [s*32, s*32+32) ----
    f32x4 gacc[4][2] = {};
    #pragma unroll
    for (int f = 0; f < 4; ++f)
      #pragma unroll
      for (int g = 0; g < 2; ++g)
        gacc[f][g] = __builtin_amdgcn_mfma_f32_16x16x32_bf16(fa0[f], fb0[g], gacc[f][g], 0, 0, 0);
    #pragma unroll
    for (int k0 = 32; k0 < 128; k0 += 32) {
      bf16x8 fa[4], fb[2];
      #pragma unroll
      for (int f = 0; f < 4; ++f)
        fa[f] = *(const bf16x8*)(W2L + (w * 64 + f * 16 + lm) * 128 + k0 + lq * 8);
      #pragma unroll
      for (int g = 0; g < 2; ++g)
        fb[g] = *(const bf16x8*)(H_b + (s * 32 + g * 16 + lm) * 128 + k0 + lq * 8);
      #pragma unroll
      for (int f = 0; f < 4; ++f)
        #pragma unroll
        for (int g = 0; g < 2; ++g)
          gacc[f][g] = __builtin_amdgcn_mfma_f32_16x16x32_bf16(fa[f], fb[g], gacc[f][g], 0, 0, 0);
    }
    #pragma unroll
    for (int f = 0; f < 4; ++f) {
      int n = w * 16 + f * 4 + lq;             // c = n*4 + reg(k)
      #pragma unroll
      for (int g = 0; g < 2; ++g) {
        int jl = g * 16 + lm;
        union { unsigned short h4[4]; uint2 v; } u;
        u.h4[0] = f2bf(gacc[f][g][0]); u.h4[1] = f2bf(gacc[f][g][1]);
        u.h4[2] = f2bf(gacc[f][g][2]); u.h4[3] = f2bf(gacc[f][g][3]);
        *(uint2*)(&Gs[n * GS_PITCH + jl * 4]) = u.v;
      }
    }
    __syncthreads();   // drains Gs writes AND the Es DMA (vmcnt(0) at barrier)

    // ---- phase 2: macc += Es @ Gs^T, all LDS ----
    #pragma unroll
    for (int kt = 0; kt < 4; ++kt) {
      bf16x8 ea[2], fb[4];
      #pragma unroll
      for (int f = 0; f < 2; ++f) {
        int i  = wr * 32 + f * 16 + lm;        // i & 15 == lm
        int cb = (kt * 4 + lq) ^ lm;           // un-swizzle
        ea[f] = *(const bf16x8*)(Es + i * 128 + cb * 8);
      }
      #pragma unroll
      for (int g = 0; g < 4; ++g)
        fb[g] = *(const bf16x8*)(&Gs[(wc * 64 + g * 16 + lm) * GS_PITCH + kt * 32 + lq * 8]);
      #pragma unroll
      for (int f = 0; f < 2; ++f)
        #pragma unroll
        for (int g = 0; g < 4; ++g)
          macc[f][g] = __builtin_amdgcn_mfma_f32_16x16x32_bf16(ea[f], fb[g], macc[f][g], 0, 0, 0);
    }
  }

  // ---- phase 1b: sacc = Hin @ SW (cols 512..639 of W2L), same (i,n) map ----
  f32x4 sacc[2][4] = {};
  #pragma unroll
  for (int k0 = 0; k0 < 128; k0 += 32) {
    bf16x8 fa[2], fb[4];
    #pragma unroll
    for (int f = 0; f < 2; ++f)
      fa[f] = *(const bf16x8*)(H_b + (wr * 32 + f * 16 + lm) * 128 + k0 + lq * 8);
    #pragma unroll
    for (int g = 0; g < 4; ++g)
      fb[g] = *(const bf16x8*)(W2L + (512 + wc * 64 + g * 16 + lm) * 128 + k0 + lq * 8);
    #pragma unroll
    for (int f = 0; f < 2; ++f)
      #pragma unroll
      for (int g = 0; g < 4; ++g)
        sacc[f][g] = __builtin_amdgcn_mfma_f32_16x16x32_bf16(fa[f], fb[g], sacc[f][g], 0, 0, 0);
  }

  // ---- epilogue: fuse, stage rows in Es, coalesced 64B/thread stores ----
  const float* dvb = Dv + b * 128;
  __syncthreads();   // all phase-2 Es readers done before overwrite
  #pragma unroll
  for (int f = 0; f < 2; ++f) {
    int i0 = wr * 32 + f * 16 + lq * 4;
    f32x4 d = *(const f32x4*)(dvb + i0);
    #pragma unroll
    for (int g = 0; g < 4; ++g) {
      int n = wc * 64 + g * 16 + lm;
      #pragma unroll
      for (int r = 0; r < 4; ++r) {
        float v = fmaf(macc[f][g][r], d[r], sacc[f][g][r]);
        Es[(i0 + r) * 128 + n] = f2bf(1.0f / (1.0f + __expf(-v)));
      }
    }
  }
  __syncthreads();
  unsigned short* O_b = Hout + (size_t)b * 16384;
  {
    int off = tid * 32;                        // 32 ushorts = 64 B per thread
    f32x4 v0 = *(const f32x4*)(Es + off);
    f32x4 v1 = *(const f32x4*)(Es + off + 8);
    f32x4 v2 = *(const f32x4*)(Es + off + 16);
    f32x4 v3 = *(const f32x4*)(Es + off + 24);
    *(f32x4*)(O_b + off)      = v0;
    *(f32x4*)(O_b + off + 8)  = v1;
    *(f32x4*)(O_b + off + 16) = v2;
    *(f32x4*)(O_b + off + 24) = v3;
  }

  if (DOMLP) {
    __syncthreads();   // O_b stores drained (vmcnt0 at barrier); Gs free
    float* W1s = (float*)Gs;            // 2560 floats
    float* b1s = W1s + 2560;            // 20
    float* W2s = b1s + 32;              // 20
    float* red = W2s + 32;              // 512
    for (int i = tid; i < 2560; i += 512) W1s[i] = W1[i];
    if (tid < 20) { b1s[tid] = b1[tid]; W2s[tid] = W2w[tid]; }
    __syncthreads();

    float sv = 0.0f;
    if (tid < 128) {
      const unsigned short* hr = O_b + (size_t)tid * 128;
      float h[20];
      #pragma unroll
      for (int j = 0; j < 20; ++j) h[j] = b1s[j];
      for (int m8 = 0; m8 < 128; m8 += 8) {
        f32x4 pk = *(const f32x4*)(hr + m8);
        const unsigned short* us = (const unsigned short*)&pk;
        #pragma unroll
        for (int e = 0; e < 8; ++e) {
          float x = bf2f(us[e]);
          #pragma unroll
          for (int j = 0; j < 20; ++j) h[j] = fmaf(x, W1s[(m8 + e) * 20 + j], h[j]);
        }
      }
      float v = b2[0];
      #pragma unroll
      for (int j = 0; j < 20; ++j) {
        float t = h[j];
        t = fmaxf(t, 0.1f * t);
        v = fmaf(t, W2s[j], v);
      }
      sv = 1.0f / (1.0f + __expf(-v));
    }

    red[tid] = sv;
    __syncthreads();
    #pragma unroll
    for (int off = 256; off > 0; off >>= 1) {
      if (tid < off) red[tid] += red[tid + off];
      __syncthreads();
    }
    if (tid == 0) {
      atomicAdd(Sum, red[0]);
      __threadfence();
      int c = atomicAdd(Cnt, 1);
      if (c == BB - 1) {
        float tot = atomicAdd(Sum, 0.0f);
        out[0] = tot * (1.0f / 65536.0f);
      }
    }
  }
}

// ---------------------------------------------------------------------------
extern "C" void kernel_launch(void* const* d_in, const int* in_sizes, int n_in,
                              void* d_out, int out_size, void* d_ws, size_t ws_size,
                              hipStream_t stream) {
  (void)in_sizes; (void)n_in; (void)out_size; (void)ws_size;
  const float* H   = (const float*)d_in[0];
  const float* E   = (const float*)d_in[1];
  const float* RW1 = (const float*)d_in[2];
  const float* SW1 = (const float*)d_in[3];
  const float* RW2 = (const float*)d_in[4];
  const float* SW2 = (const float*)d_in[5];
  const float* RW3 = (const float*)d_in[6];
  const float* SW3 = (const float*)d_in[7];
  const float* W1  = (const float*)d_in[8];
  const float* b1  = (const float*)d_in[9];
  const float* W2  = (const float*)d_in[10];
  const float* b2  = (const float*)d_in[11];
  float* out = (float*)d_out;

  char* w = (char*)d_ws;
  float*          wsD   = (float*)w;           w += (size_t)65536 * 4;
  unsigned short* wsEb  = (unsigned short*)w;  w += (size_t)33554432 * 2;   // 64 MB
  unsigned short* wsHa  = (unsigned short*)w;  w += (size_t)8388608 * 2;
  unsigned short* wsHb  = (unsigned short*)w;  w += (size_t)8388608 * 2;
  unsigned short* wsHc  = (unsigned short*)w;  w += (size_t)8388608 * 2;
  unsigned short* wsHd  = (unsigned short*)w;  w += (size_t)8388608 * 2;
  unsigned short* wsW2  = (unsigned short*)w;  w += (size_t)3 * 81920 * 2;
  float*          wsSum = (float*)w;           w += 64;
  int*            wsCnt = (int*)w;             w += 64;

  // 4 dispatches: prep, layer1, layer2, layer3+MLP+final
  k_prep<<<21440, 256, 0, stream>>>(E, H, RW1, SW1, RW2, SW2, RW3, SW3,
                                    wsEb, wsHa, wsW2, wsD, wsSum, wsCnt);

  k_layer<0><<<BB, 512, 0, stream>>>(wsEb, wsHa, wsW2,          wsD, wsHb,
                                     W1, b1, W2, b2, wsSum, wsCnt, out);
  k_layer<0><<<BB, 512, 0, stream>>>(wsEb, wsHb, wsW2 + 81920,  wsD, wsHc,
                                     W1, b1, W2, b2, wsSum, wsCnt, out);
  k_layer<1><<<BB, 512, 0, stream>>>(wsEb, wsHc, wsW2 + 163840, wsD, wsHd,
                                     W1, b1, W2, b2, wsSum, wsCnt, out);
}